// Round 5
// baseline (174.735 us; speedup 1.0000x reference)
//
#include <hip/hip_runtime.h>
#include <math.h>

#define B_ 2
#define C_ 96
#define L_ 4096
#define N_ 16
#define R_ 6
#define K_ 4
#define D38 38
#define D40 40

typedef unsigned short ushort_t;
typedef unsigned int uint_t;

__device__ __forceinline__ uint_t bf16rtn(float f) {
    uint_t u = __float_as_uint(f);
    return (u + 0x7FFFu + ((u >> 16) & 1u)) >> 16;
}
__device__ __forceinline__ float bflo(uint_t p) { return __uint_as_float(p << 16); }
__device__ __forceinline__ float bfhi(uint_t p) { return __uint_as_float(p & 0xFFFF0000u); }

// ---------------------------------------------------------------------------
// Prep: [0,60) weight transpose (K,38,C)->(K,C,40 zero-pad); [60,252) x->xT
// 64x64 transposes; block 252 computes the k-uniformity flag.
// ---------------------------------------------------------------------------
__global__ __launch_bounds__(256) void prep_kernel(
    const float* __restrict__ w, const float* __restrict__ x,
    const float* __restrict__ dpw, const float* __restrict__ dpb,
    float* __restrict__ wt, float* __restrict__ xT, int* __restrict__ flag)
{
    int blk = blockIdx.x;
    int tid = threadIdx.x;
    if (blk < 60) {
        int i = blk * 256 + tid;
        if (i < K_ * C_ * D40) {
            int k   = i / (C_ * D40);
            int rem = i % (C_ * D40);
            int cc  = rem / D40;
            int dd  = rem % D40;
            wt[i] = (dd < D38) ? w[((size_t)k * D38 + dd) * C_ + cc] : 0.f;
        }
    } else if (blk < 60 + B_ * C_) {
        __shared__ float t[64][65];
        int bc = blk - 60;
        const float* src = x  + (size_t)bc * L_;
        float*       dst = xT + (size_t)bc * L_;
        int r0  = tid >> 6;
        int col = tid & 63;
        #pragma unroll
        for (int rr = 0; rr < 16; ++rr) {
            int row = rr * 4 + r0;
            t[row][col] = src[row * 64 + col];
        }
        __syncthreads();
        #pragma unroll
        for (int rr = 0; rr < 16; ++rr) {
            int row = rr * 4 + r0;
            dst[row * 64 + col] = t[col][row];
        }
    } else {
        bool ok = true;
        const int S = D38 * C_;
        for (int i = tid; i < S; i += 256)
            ok = ok && (w[2 * S + i] == w[i]) && (w[3 * S + i] == w[S + i]);
        const int S2 = C_ * R_;
        for (int i = tid; i < S2; i += 256)
            ok = ok && (dpw[2 * S2 + i] == dpw[i]) && (dpw[3 * S2 + i] == dpw[S2 + i]);
        if (tid < C_)
            ok = ok && (dpb[2 * C_ + tid] == dpb[tid]) && (dpb[3 * C_ + tid] == dpb[C_ + tid]);
        __shared__ int sok[4];
        unsigned long long m = __ballot(ok);
        if ((tid & 63) == 0) sok[tid >> 6] = (m == 0xFFFFFFFFFFFFFFFFull) ? 1 : 0;
        __syncthreads();
        if (tid == 0) flag[0] = sok[0] & sok[1] & sok[2] & sok[3];
    }
}

// ---------------------------------------------------------------------------
// Kernel 1: projection, fully LDS-staged (x tile + weights). If flag && k>=2
// the block exits (its outputs are flips of k-2, read that way by scan).
// grid = B*K*(L/64) = 512 blocks x 512 threads.
// ---------------------------------------------------------------------------
__global__ __launch_bounds__(512) void proj_kernel(
    const float* __restrict__ x, const float* __restrict__ xT,
    const float* __restrict__ wt, const float* __restrict__ dpw,
    const float* __restrict__ dpb, const int* __restrict__ flagp,
    float* __restrict__ ws_delta, ushort_t* __restrict__ ws_Bm,
    ushort_t* __restrict__ ws_Cm)
{
    __shared__ float Xs[C_][64];         // 24 KB
    __shared__ float Wsh[C_ * D40];      // 15 KB
    __shared__ float Dwh[C_ * 8];        // 3 KB (6 w + bias, pad 8)
    __shared__ float T2[2][64][41];      // 21 KB

    int tile = blockIdx.x;
    int lt   = tile & 63;
    int bk   = tile >> 6;
    int k    = bk & 3;
    int b    = bk >> 2;
    if (k >= 2 && flagp[0]) return;

    int tid  = threadIdx.x;
    int l0   = tid & 63;
    int dq   = (tid >> 6) & 3;
    int ch   = tid >> 8;
    int base = dq * 10;                  // cols 38,39 are zero-padded

    // ---- stage x tile (m-order), proj weights, delta weights/bias
    int mt0 = (k >= 2) ? (L_ - 64 * (lt + 1)) : (lt * 64);
    const float* src = ((k & 1) ? xT : x) + (size_t)b * C_ * L_ + mt0;
    #pragma unroll
    for (int s = 0; s < 3; ++s) {
        int idx = tid + s * 512;         // 0..1535 = 96*16 float4s
        int row = idx >> 4, c4 = (idx & 15) << 2;
        *(float4*)&Xs[row][c4] = *(const float4*)(src + (size_t)row * L_ + c4);
    }
    const float* wk = wt + (size_t)k * C_ * D40;
    #pragma unroll
    for (int s = 0; s < 2; ++s) {
        int idx = tid + s * 512;
        if (idx < (C_ * D40 / 4))
            *(float4*)&Wsh[idx * 4] = *(const float4*)(wk + idx * 4);
    }
    if (tid < C_) {
        const float* dwk = dpw + (size_t)k * C_ * R_ + tid * R_;
        #pragma unroll
        for (int r = 0; r < R_; ++r) Dwh[tid * 8 + r] = dwk[r];
        Dwh[tid * 8 + 6] = dpb[k * C_ + tid];
    }
    __syncthreads();

    int xi = (k >= 2) ? (63 - l0) : l0;
    float acc[10];
    #pragma unroll
    for (int t = 0; t < 10; ++t) acc[t] = 0.f;
    int c0 = ch * 48;
    #pragma unroll 4
    for (int cc = 0; cc < 48; ++cc) {
        int c = c0 + cc;
        float xv = Xs[c][xi];
        const float* wc = &Wsh[c * D40 + base];   // wave-uniform -> broadcast
        #pragma unroll
        for (int t = 0; t < 10; ++t) acc[t] = fmaf(xv, wc[t], acc[t]);
    }
    #pragma unroll
    for (int t = 0; t < 10; ++t) T2[ch][l0][base + t] = acc[t];
    __syncthreads();

    // ---- B/C bf16 coalesced stores (uint2 per thread)
    {
        int lq = tid >> 3, sub = tid & 7;
        int buf = sub >> 2, q = sub & 3;
        int col = R_ + buf * 16 + 4 * q;
        float v0 = T2[0][lq][col]     + T2[1][lq][col];
        float v1 = T2[0][lq][col + 1] + T2[1][lq][col + 1];
        float v2 = T2[0][lq][col + 2] + T2[1][lq][col + 2];
        float v3 = T2[0][lq][col + 3] + T2[1][lq][col + 3];
        uint_t p0 = bf16rtn(v0) | (bf16rtn(v1) << 16);
        uint_t p1 = bf16rtn(v2) | (bf16rtn(v3) << 16);
        ushort_t* dst = buf ? ws_Cm : ws_Bm;
        *(uint2*)(dst + ((size_t)bk * L_ + lt * 64 + lq) * N_ + 4 * q) =
            make_uint2(p0, p1);
    }

    // ---- delta projection + softplus (c wave-uniform, stores coalesced)
    float ar[R_];
    #pragma unroll
    for (int r = 0; r < R_; ++r) ar[r] = T2[0][l0][r] + T2[1][l0][r];
    float* dlt = ws_delta + (size_t)bk * C_ * L_ + lt * 64 + l0;
    int cq = ch * 4 + dq;
    #pragma unroll 2
    for (int cc = 0; cc < 12; ++cc) {
        int c = cc * 8 + cq;
        float s = Dwh[c * 8 + 6];
        #pragma unroll
        for (int r = 0; r < R_; ++r) s = fmaf(ar[r], Dwh[c * 8 + r], s);
        float sp = fmaxf(s, 0.f) + log1pf(__expf(-fabsf(s)));
        dlt[(size_t)c * L_] = sp;
    }
}

// ---------------------------------------------------------------------------
// Kernel 2: selective scan, 1024 threads per channel. Thread (g,q): chunk of
// 16 l's, n-quad q. bf16 B/C; pass-1 caches r_j and du*B quads in registers
// so pass-2 does no B reload / exp / delta read. flag => k>=2 reads k-2's
// delta/B/C reversed.
// ---------------------------------------------------------------------------
#define SR 17

__global__ __launch_bounds__(1024, 8) void scan_kernel(
    const float* __restrict__ ws_delta, const float* __restrict__ x,
    const float* __restrict__ xT, const ushort_t* __restrict__ ws_Bm,
    const ushort_t* __restrict__ ws_Cm, const float* __restrict__ A_log,
    const float* __restrict__ Ds, const int* __restrict__ flagp,
    float* __restrict__ out)
{
    __shared__ float s_d[16][16 * SR];
    __shared__ float s_u[16][16 * SR];
    __shared__ float s_wA[16][N_];
    __shared__ float s_wB[16][N_];

    int chn = blockIdx.x;
    int c  = chn % C_;
    int k  = (chn / C_) % K_;
    int b  = chn / (C_ * K_);
    int d  = k * C_ + c;
    bool flip = (k >= 2) && (flagp[0] != 0);
    int bk2   = flip ? (b * K_ + k - 2) : (b * K_ + k);
    int sch   = flip ? (chn - 2 * C_) : chn;

    int tid  = threadIdx.x;
    int w    = tid >> 6;
    int lane = tid & 63;
    int i    = lane >> 2;
    int q    = lane & 3;
    int g    = w * 16 + i;

    float A4[4];
    bool okl = true;
    #pragma unroll
    for (int e = 0; e < 4; ++e) {
        A4[e] = -__expf(A_log[(size_t)d * N_ + 4 * q + e]);
        okl &= (fabsf(A4[e] + (float)(4 * q + e + 1)) < 1e-3f);
    }
    int fast = __all(okl);

    // ---- stage delta + u (per-wave private; no barrier needed)
    {
        int e = lane * 4;
        int row = e >> 4, col = e & 15;
        const float* dp = ws_delta + (size_t)sch * L_;
        float4 v;
        if (!flip) v = *(const float4*)(dp + w * 256 + e);
        else {
            float4 t4 = *(const float4*)(dp + (L_ - 4 - w * 256 - e));
            v = make_float4(t4.w, t4.z, t4.y, t4.x);
        }
        *(float4*)(s_d[w] + row * SR + col) = v;

        const float* usrc = ((k & 1) ? xT : x) + ((size_t)b * C_ + c) * L_;
        if (k < 2) {
            *(float4*)(s_u[w] + row * SR + col) = *(const float4*)(usrc + w * 256 + e);
        } else {
            float4 t4 = *(const float4*)(usrc + (L_ - 4 - w * 256 - e));
            *(float4*)(s_u[w] + row * SR + col) = make_float4(t4.w, t4.z, t4.y, t4.x);
        }
    }

    const float* sd = s_d[w] + i * SR;
    const float* su = s_u[w] + i * SR;
    const uint2* B2 = (const uint2*)(ws_Bm + (size_t)bk2 * ((size_t)L_ * N_));
    const uint2* C2 = (const uint2*)(ws_Cm + (size_t)bk2 * ((size_t)L_ * N_));
    int l_base = g * 16;
    int ib = (flip ? (L_ - 1 - l_base) : l_base) * 4 + q;
    int st = flip ? -4 : 4;

    float Ac[4] = {1.f, 1.f, 1.f, 1.f};
    float Bc[4] = {0.f, 0.f, 0.f, 0.f};
    float rj[16];
    float dB0[16], dB1[16], dB2[16], dB3[16];

    // ---- pass 1: chunk composite (+ register cache of r and du*B)
    if (fast) {
        float Rc = 1.f;
        #pragma unroll
        for (int j = 0; j < 16; ++j) {
            float dl = sd[j], ul = su[j], du = dl * ul;
            uint2 bv = B2[ib + j * st];
            float b0 = bflo(bv.x), b1 = bfhi(bv.x), b2 = bflo(bv.y), b3 = bfhi(bv.y);
            float r  = __expf(-dl);
            rj[j] = r;
            float r2 = r * r, r4 = r2 * r2, r8 = r4 * r4;
            float t0 = (q & 1) ? r4 : 1.f;
            float s0 = (q & 2) ? t0 * r8 : t0;
            float a0 = s0 * r, a1 = s0 * r2, a2 = a1 * r, a3 = s0 * r4;
            float d0 = du * b0, d1 = du * b1, d2 = du * b2, d3 = du * b3;
            dB0[j] = d0; dB1[j] = d1; dB2[j] = d2; dB3[j] = d3;
            Bc[0] = fmaf(a0, Bc[0], d0);
            Bc[1] = fmaf(a1, Bc[1], d1);
            Bc[2] = fmaf(a2, Bc[2], d2);
            Bc[3] = fmaf(a3, Bc[3], d3);
            Rc *= r;
        }
        float R2 = Rc * Rc, R4 = R2 * R2, R8 = R4 * R4;
        float t0 = (q & 1) ? R4 : 1.f;
        float s0 = (q & 2) ? t0 * R8 : t0;
        Ac[0] = s0 * Rc; Ac[1] = s0 * R2; Ac[2] = Ac[1] * Rc; Ac[3] = s0 * R4;
    } else {
        #pragma unroll 4
        for (int j = 0; j < 16; ++j) {
            float dl = sd[j], ul = su[j], du = dl * ul;
            uint2 bv = B2[ib + j * st];
            float bq0 = bflo(bv.x), bq1 = bfhi(bv.x), bq2 = bflo(bv.y), bq3 = bfhi(bv.y);
            float a0 = __expf(dl * A4[0]), a1 = __expf(dl * A4[1]);
            float a2 = __expf(dl * A4[2]), a3 = __expf(dl * A4[3]);
            Bc[0] = fmaf(a0, Bc[0], du * bq0); Ac[0] *= a0;
            Bc[1] = fmaf(a1, Bc[1], du * bq1); Ac[1] *= a1;
            Bc[2] = fmaf(a2, Bc[2], du * bq2); Ac[2] *= a2;
            Bc[3] = fmaf(a3, Bc[3], du * bq3); Ac[3] *= a3;
        }
    }

    // ---- intra-wave inclusive scan over 16 chunks
    #pragma unroll
    for (int s = 1; s < 16; s <<= 1) {
        float pA[4], pB[4];
        #pragma unroll
        for (int e = 0; e < 4; ++e) {
            pA[e] = __shfl_up(Ac[e], 4 * s, 64);
            pB[e] = __shfl_up(Bc[e], 4 * s, 64);
        }
        if (i >= s) {
            #pragma unroll
            for (int e = 0; e < 4; ++e) {
                Bc[e] = fmaf(Ac[e], pB[e], Bc[e]);
                Ac[e] *= pA[e];
            }
        }
    }

    // ---- inter-wave: wave 0 rescans the 16 wave-composites
    if (i == 15) {
        #pragma unroll
        for (int e = 0; e < 4; ++e) {
            s_wA[w][4 * q + e] = Ac[e];
            s_wB[w][4 * q + e] = Bc[e];
        }
    }
    __syncthreads();
    if (w == 0) {
        float wA[4], wB[4];
        #pragma unroll
        for (int e = 0; e < 4; ++e) {
            wA[e] = s_wA[i][4 * q + e];
            wB[e] = s_wB[i][4 * q + e];
        }
        #pragma unroll
        for (int s = 1; s < 16; s <<= 1) {
            float pA[4], pB[4];
            #pragma unroll
            for (int e = 0; e < 4; ++e) {
                pA[e] = __shfl_up(wA[e], 4 * s, 64);
                pB[e] = __shfl_up(wB[e], 4 * s, 64);
            }
            if (i >= s) {
                #pragma unroll
                for (int e = 0; e < 4; ++e) {
                    wB[e] = fmaf(wA[e], pB[e], wB[e]);
                    wA[e] *= pA[e];
                }
            }
        }
        #pragma unroll
        for (int e = 0; e < 4; ++e) s_wB[i][4 * q + e] = wB[e];
    }
    __syncthreads();

    float h[4] = {0.f, 0.f, 0.f, 0.f};
    if (w > 0) {
        #pragma unroll
        for (int e = 0; e < 4; ++e) h[e] = s_wB[w - 1][4 * q + e];
    }
    {
        float pA[4], pB[4];
        #pragma unroll
        for (int e = 0; e < 4; ++e) {
            pA[e] = __shfl_up(Ac[e], 4, 64);
            pB[e] = __shfl_up(Bc[e], 4, 64);
        }
        if (i > 0) {
            #pragma unroll
            for (int e = 0; e < 4; ++e) h[e] = fmaf(pA[e], h[e], pB[e]);
        }
    }

    // ---- pass 2: apply + output
    float Dd = Ds[d];
    int osel = (k == 0) ? 0 : (k == 2) ? 1 : (k == 1) ? 2 : 3;
    float* ob = out + ((size_t)osel * B_ + b) * ((size_t)C_ * L_) + (size_t)c * L_;

    if (fast) {
        #pragma unroll
        for (int j = 0; j < 16; ++j) {
            uint2 cv = C2[ib + j * st];
            float c0v = bflo(cv.x), c1v = bfhi(cv.x), c2v = bflo(cv.y), c3v = bfhi(cv.y);
            float r = rj[j];
            float r2 = r * r, r4 = r2 * r2, r8 = r4 * r4;
            float t0 = (q & 1) ? r4 : 1.f;
            float s0 = (q & 2) ? t0 * r8 : t0;
            float a0 = s0 * r, a1 = s0 * r2, a2 = a1 * r, a3 = s0 * r4;
            h[0] = fmaf(a0, h[0], dB0[j]);
            h[1] = fmaf(a1, h[1], dB1[j]);
            h[2] = fmaf(a2, h[2], dB2[j]);
            h[3] = fmaf(a3, h[3], dB3[j]);
            float y = h[0] * c0v;
            y = fmaf(h[1], c1v, y);
            y = fmaf(h[2], c2v, y);
            y = fmaf(h[3], c3v, y);
            y += __shfl_xor(y, 1, 64);
            y += __shfl_xor(y, 2, 64);
            if (q == 0) {
                y = fmaf(Dd, su[j], y);
                int l = g * 16 + j;
                int idx;
                if (k == 0)      idx = l;
                else if (k == 2) idx = L_ - 1 - l;
                else if (k == 1) idx = ((l & 63) << 6) | (l >> 6);
                else { int mm = L_ - 1 - l; idx = ((mm & 63) << 6) | (mm >> 6); }
                ob[idx] = y;
            }
        }
    } else {
        #pragma unroll 4
        for (int j = 0; j < 16; ++j) {
            float dl = sd[j], ul = su[j], du = dl * ul;
            uint2 bv = B2[ib + j * st];
            uint2 cv = C2[ib + j * st];
            float bq0 = bflo(bv.x), bq1 = bfhi(bv.x), bq2 = bflo(bv.y), bq3 = bfhi(bv.y);
            float c0v = bflo(cv.x), c1v = bfhi(cv.x), c2v = bflo(cv.y), c3v = bfhi(cv.y);
            float a0 = __expf(dl * A4[0]), a1 = __expf(dl * A4[1]);
            float a2 = __expf(dl * A4[2]), a3 = __expf(dl * A4[3]);
            h[0] = fmaf(a0, h[0], du * bq0);
            h[1] = fmaf(a1, h[1], du * bq1);
            h[2] = fmaf(a2, h[2], du * bq2);
            h[3] = fmaf(a3, h[3], du * bq3);
            float y = h[0] * c0v;
            y = fmaf(h[1], c1v, y);
            y = fmaf(h[2], c2v, y);
            y = fmaf(h[3], c3v, y);
            y += __shfl_xor(y, 1, 64);
            y += __shfl_xor(y, 2, 64);
            if (q == 0) {
                y = fmaf(Dd, ul, y);
                int l = g * 16 + j;
                int idx;
                if (k == 0)      idx = l;
                else if (k == 2) idx = L_ - 1 - l;
                else if (k == 1) idx = ((l & 63) << 6) | (l >> 6);
                else { int mm = L_ - 1 - l; idx = ((mm & 63) << 6) | (mm >> 6); }
                ob[idx] = y;
            }
        }
    }
}

// ---------------------------------------------------------------------------
extern "C" void kernel_launch(void* const* d_in, const int* in_sizes, int n_in,
                              void* d_out, int out_size, void* d_ws, size_t ws_size,
                              hipStream_t stream) {
    const float* x     = (const float*)d_in[0];
    const float* xpw   = (const float*)d_in[1];
    const float* dpw   = (const float*)d_in[2];
    const float* dpb   = (const float*)d_in[3];
    const float* A_log = (const float*)d_in[4];
    const float* Ds    = (const float*)d_in[5];
    float* out = (float*)d_out;

    float* ws = (float*)d_ws;
    const size_t dL  = (size_t)B_ * K_ * C_ * L_;   // 3,145,728 floats
    const size_t bcL = (size_t)B_ * K_ * L_ * N_;   //   524,288 elements
    const size_t xL  = (size_t)B_ * C_ * L_;        //   786,432 floats
    float*    ws_delta = ws;
    ushort_t* ws_Bm    = (ushort_t*)(ws + dL);      // bcL ushorts
    ushort_t* ws_Cm    = ws_Bm + bcL;               // bcL ushorts
    float*    ws_xT    = ws + dL + bcL;             // (2 bf16 arrays = bcL floats)
    float*    ws_Wt    = ws_xT + xL;                // K*C*40 floats
    int*      ws_flag  = (int*)(ws_Wt + (size_t)K_ * C_ * D40);

    prep_kernel<<<60 + B_ * C_ + 1, 256, 0, stream>>>(
        xpw, x, dpw, dpb, ws_Wt, ws_xT, ws_flag);
    proj_kernel<<<B_ * K_ * (L_ / 64), 512, 0, stream>>>(
        x, ws_xT, ws_Wt, dpw, dpb, ws_flag, ws_delta, ws_Bm, ws_Cm);
    scan_kernel<<<B_ * K_ * C_, 1024, 0, stream>>>(
        ws_delta, x, ws_xT, ws_Bm, ws_Cm, A_log, Ds, ws_flag, out);
}

// Round 6
// 86.281 us; speedup vs baseline: 2.0252x; 2.0252x over previous
//
#include <hip/hip_runtime.h>
#include <math.h>

#define B_ 2
#define C_ 96
#define L_ 4096
#define N_ 16
#define R_ 6
#define K_ 4
#define D38 38
#define D40 40

typedef unsigned short ushort_t;
typedef unsigned int uint_t;

__device__ __forceinline__ uint_t bf16rtn(float f) {
    uint_t u = __float_as_uint(f);
    return (u + 0x7FFFu + ((u >> 16) & 1u)) >> 16;
}
__device__ __forceinline__ float bflo(uint_t p) { return __uint_as_float(p << 16); }
__device__ __forceinline__ float bfhi(uint_t p) { return __uint_as_float(p & 0xFFFF0000u); }

// ---------------------------------------------------------------------------
// Prep: [0,60) weight transpose (K,38,C)->(K,C,40 zero-pad); [60,252) x->xT
// 64x64 transposes; block 252 computes the k-uniformity flag.
// ---------------------------------------------------------------------------
__global__ __launch_bounds__(256) void prep_kernel(
    const float* __restrict__ w, const float* __restrict__ x,
    const float* __restrict__ dpw, const float* __restrict__ dpb,
    float* __restrict__ wt, float* __restrict__ xT, int* __restrict__ flag)
{
    int blk = blockIdx.x;
    int tid = threadIdx.x;
    if (blk < 60) {
        int i = blk * 256 + tid;
        if (i < K_ * C_ * D40) {
            int k   = i / (C_ * D40);
            int rem = i % (C_ * D40);
            int cc  = rem / D40;
            int dd  = rem % D40;
            wt[i] = (dd < D38) ? w[((size_t)k * D38 + dd) * C_ + cc] : 0.f;
        }
    } else if (blk < 60 + B_ * C_) {
        __shared__ float t[64][65];
        int bc = blk - 60;
        const float* src = x  + (size_t)bc * L_;
        float*       dst = xT + (size_t)bc * L_;
        int r0  = tid >> 6;
        int col = tid & 63;
        #pragma unroll
        for (int rr = 0; rr < 16; ++rr) {
            int row = rr * 4 + r0;
            t[row][col] = src[row * 64 + col];
        }
        __syncthreads();
        #pragma unroll
        for (int rr = 0; rr < 16; ++rr) {
            int row = rr * 4 + r0;
            dst[row * 64 + col] = t[col][row];
        }
    } else {
        bool ok = true;
        const int S = D38 * C_;
        for (int i = tid; i < S; i += 256)
            ok = ok && (w[2 * S + i] == w[i]) && (w[3 * S + i] == w[S + i]);
        const int S2 = C_ * R_;
        for (int i = tid; i < S2; i += 256)
            ok = ok && (dpw[2 * S2 + i] == dpw[i]) && (dpw[3 * S2 + i] == dpw[S2 + i]);
        if (tid < C_)
            ok = ok && (dpb[2 * C_ + tid] == dpb[tid]) && (dpb[3 * C_ + tid] == dpb[C_ + tid]);
        __shared__ int sok[4];
        unsigned long long m = __ballot(ok);
        if ((tid & 63) == 0) sok[tid >> 6] = (m == 0xFFFFFFFFFFFFFFFFull) ? 1 : 0;
        __syncthreads();
        if (tid == 0) flag[0] = sok[0] & sok[1] & sok[2] & sok[3];
    }
}

// ---------------------------------------------------------------------------
// Kernel 1: projection, fully LDS-staged (x tile + weights). If flag && k>=2
// the block exits (its outputs are flips of k-2, read that way by scan).
// grid = B*K*(L/64) = 512 blocks x 512 threads.
// ---------------------------------------------------------------------------
__global__ __launch_bounds__(512) void proj_kernel(
    const float* __restrict__ x, const float* __restrict__ xT,
    const float* __restrict__ wt, const float* __restrict__ dpw,
    const float* __restrict__ dpb, const int* __restrict__ flagp,
    float* __restrict__ ws_delta, ushort_t* __restrict__ ws_Bm,
    ushort_t* __restrict__ ws_Cm)
{
    __shared__ float Xs[C_][64];         // 24 KB
    __shared__ float Wsh[C_ * D40];      // 15 KB
    __shared__ float Dwh[C_ * 8];        // 3 KB (6 w + bias, pad 8)
    __shared__ float T2[2][64][41];      // 21 KB

    int tile = blockIdx.x;
    int lt   = tile & 63;
    int bk   = tile >> 6;
    int k    = bk & 3;
    int b    = bk >> 2;
    if (k >= 2 && flagp[0]) return;

    int tid  = threadIdx.x;
    int l0   = tid & 63;
    int dq   = (tid >> 6) & 3;
    int ch   = tid >> 8;
    int base = dq * 10;                  // cols 38,39 are zero-padded

    // ---- stage x tile (m-order), proj weights, delta weights/bias
    int mt0 = (k >= 2) ? (L_ - 64 * (lt + 1)) : (lt * 64);
    const float* src = ((k & 1) ? xT : x) + (size_t)b * C_ * L_ + mt0;
    #pragma unroll
    for (int s = 0; s < 3; ++s) {
        int idx = tid + s * 512;         // 0..1535 = 96*16 float4s
        int row = idx >> 4, c4 = (idx & 15) << 2;
        *(float4*)&Xs[row][c4] = *(const float4*)(src + (size_t)row * L_ + c4);
    }
    const float* wk = wt + (size_t)k * C_ * D40;
    #pragma unroll
    for (int s = 0; s < 2; ++s) {
        int idx = tid + s * 512;
        if (idx < (C_ * D40 / 4))
            *(float4*)&Wsh[idx * 4] = *(const float4*)(wk + idx * 4);
    }
    if (tid < C_) {
        const float* dwk = dpw + (size_t)k * C_ * R_ + tid * R_;
        #pragma unroll
        for (int r = 0; r < R_; ++r) Dwh[tid * 8 + r] = dwk[r];
        Dwh[tid * 8 + 6] = dpb[k * C_ + tid];
    }
    __syncthreads();

    int xi = (k >= 2) ? (63 - l0) : l0;
    float acc[10];
    #pragma unroll
    for (int t = 0; t < 10; ++t) acc[t] = 0.f;
    int c0 = ch * 48;
    #pragma unroll 4
    for (int cc = 0; cc < 48; ++cc) {
        int c = c0 + cc;
        float xv = Xs[c][xi];
        const float* wc = &Wsh[c * D40 + base];   // wave-uniform -> broadcast
        #pragma unroll
        for (int t = 0; t < 10; ++t) acc[t] = fmaf(xv, wc[t], acc[t]);
    }
    #pragma unroll
    for (int t = 0; t < 10; ++t) T2[ch][l0][base + t] = acc[t];
    __syncthreads();

    // ---- B/C bf16 coalesced stores (uint2 per thread)
    {
        int lq = tid >> 3, sub = tid & 7;
        int buf = sub >> 2, q = sub & 3;
        int col = R_ + buf * 16 + 4 * q;
        float v0 = T2[0][lq][col]     + T2[1][lq][col];
        float v1 = T2[0][lq][col + 1] + T2[1][lq][col + 1];
        float v2 = T2[0][lq][col + 2] + T2[1][lq][col + 2];
        float v3 = T2[0][lq][col + 3] + T2[1][lq][col + 3];
        uint_t p0 = bf16rtn(v0) | (bf16rtn(v1) << 16);
        uint_t p1 = bf16rtn(v2) | (bf16rtn(v3) << 16);
        ushort_t* dst = buf ? ws_Cm : ws_Bm;
        *(uint2*)(dst + ((size_t)bk * L_ + lt * 64 + lq) * N_ + 4 * q) =
            make_uint2(p0, p1);
    }

    // ---- delta projection + softplus (c wave-uniform, stores coalesced)
    float ar[R_];
    #pragma unroll
    for (int r = 0; r < R_; ++r) ar[r] = T2[0][l0][r] + T2[1][l0][r];
    float* dlt = ws_delta + (size_t)bk * C_ * L_ + lt * 64 + l0;
    int cq = ch * 4 + dq;
    #pragma unroll 2
    for (int cc = 0; cc < 12; ++cc) {
        int c = cc * 8 + cq;
        float s = Dwh[c * 8 + 6];
        #pragma unroll
        for (int r = 0; r < R_; ++r) s = fmaf(ar[r], Dwh[c * 8 + r], s);
        float sp = fmaxf(s, 0.f) + log1pf(__expf(-fabsf(s)));
        dlt[(size_t)c * L_] = sp;
    }
}

// ---------------------------------------------------------------------------
// Kernel 2: selective scan, 1024 threads per channel. Thread (g,q): chunk of
// 16 l's, n-quad q. bf16 B/C. Only rj[16] is register-cached (16 VGPR; the
// R5 dB caches spilled -> 541 MB scratch traffic). Pass 2 reloads B/C from
// L2 and sd/su from LDS. flag => k>=2 reads k-2's delta/B/C reversed.
// ---------------------------------------------------------------------------
#define SR 17

__global__ __launch_bounds__(1024, 8) void scan_kernel(
    const float* __restrict__ ws_delta, const float* __restrict__ x,
    const float* __restrict__ xT, const ushort_t* __restrict__ ws_Bm,
    const ushort_t* __restrict__ ws_Cm, const float* __restrict__ A_log,
    const float* __restrict__ Ds, const int* __restrict__ flagp,
    float* __restrict__ out)
{
    __shared__ float s_d[16][16 * SR];
    __shared__ float s_u[16][16 * SR];
    __shared__ float s_wA[16][N_];
    __shared__ float s_wB[16][N_];

    int chn = blockIdx.x;
    int c  = chn % C_;
    int k  = (chn / C_) % K_;
    int b  = chn / (C_ * K_);
    int d  = k * C_ + c;
    bool flip = (k >= 2) && (flagp[0] != 0);
    int bk2   = flip ? (b * K_ + k - 2) : (b * K_ + k);
    int sch   = flip ? (chn - 2 * C_) : chn;

    int tid  = threadIdx.x;
    int w    = tid >> 6;
    int lane = tid & 63;
    int i    = lane >> 2;
    int q    = lane & 3;
    int g    = w * 16 + i;

    float A4[4];
    bool okl = true;
    #pragma unroll
    for (int e = 0; e < 4; ++e) {
        A4[e] = -__expf(A_log[(size_t)d * N_ + 4 * q + e]);
        okl &= (fabsf(A4[e] + (float)(4 * q + e + 1)) < 1e-3f);
    }
    int fast = __all(okl);

    // ---- stage delta + u (per-wave private; no barrier needed)
    {
        int e = lane * 4;
        int row = e >> 4, col = e & 15;
        const float* dp = ws_delta + (size_t)sch * L_;
        float4 v;
        if (!flip) v = *(const float4*)(dp + w * 256 + e);
        else {
            float4 t4 = *(const float4*)(dp + (L_ - 4 - w * 256 - e));
            v = make_float4(t4.w, t4.z, t4.y, t4.x);
        }
        *(float4*)(s_d[w] + row * SR + col) = v;

        const float* usrc = ((k & 1) ? xT : x) + ((size_t)b * C_ + c) * L_;
        if (k < 2) {
            *(float4*)(s_u[w] + row * SR + col) = *(const float4*)(usrc + w * 256 + e);
        } else {
            float4 t4 = *(const float4*)(usrc + (L_ - 4 - w * 256 - e));
            *(float4*)(s_u[w] + row * SR + col) = make_float4(t4.w, t4.z, t4.y, t4.x);
        }
    }

    const float* sd = s_d[w] + i * SR;
    const float* su = s_u[w] + i * SR;
    const uint2* B2 = (const uint2*)(ws_Bm + (size_t)bk2 * ((size_t)L_ * N_));
    const uint2* C2 = (const uint2*)(ws_Cm + (size_t)bk2 * ((size_t)L_ * N_));
    int l_base = g * 16;
    int ib = (flip ? (L_ - 1 - l_base) : l_base) * 4 + q;
    int st = flip ? -4 : 4;

    float Ac[4] = {1.f, 1.f, 1.f, 1.f};
    float Bc[4] = {0.f, 0.f, 0.f, 0.f};
    float rj[16];   // exp(-delta) cache: 16 VGPR, fits under the 8-wave cap

    // ---- pass 1: chunk composite
    if (fast) {
        float Rc = 1.f;
        #pragma unroll
        for (int j = 0; j < 16; ++j) {
            float dl = sd[j], ul = su[j], du = dl * ul;
            uint2 bv = B2[ib + j * st];
            float b0 = bflo(bv.x), b1 = bfhi(bv.x), b2 = bflo(bv.y), b3 = bfhi(bv.y);
            float r  = __expf(-dl);
            rj[j] = r;
            float r2 = r * r, r4 = r2 * r2, r8 = r4 * r4;
            float t0 = (q & 1) ? r4 : 1.f;
            float s0 = (q & 2) ? t0 * r8 : t0;
            float a0 = s0 * r, a1 = s0 * r2, a2 = a1 * r, a3 = s0 * r4;
            Bc[0] = fmaf(a0, Bc[0], du * b0);
            Bc[1] = fmaf(a1, Bc[1], du * b1);
            Bc[2] = fmaf(a2, Bc[2], du * b2);
            Bc[3] = fmaf(a3, Bc[3], du * b3);
            Rc *= r;
        }
        float R2 = Rc * Rc, R4 = R2 * R2, R8 = R4 * R4;
        float t0 = (q & 1) ? R4 : 1.f;
        float s0 = (q & 2) ? t0 * R8 : t0;
        Ac[0] = s0 * Rc; Ac[1] = s0 * R2; Ac[2] = Ac[1] * Rc; Ac[3] = s0 * R4;
    } else {
        #pragma unroll 4
        for (int j = 0; j < 16; ++j) {
            float dl = sd[j], ul = su[j], du = dl * ul;
            uint2 bv = B2[ib + j * st];
            float bq0 = bflo(bv.x), bq1 = bfhi(bv.x), bq2 = bflo(bv.y), bq3 = bfhi(bv.y);
            float a0 = __expf(dl * A4[0]), a1 = __expf(dl * A4[1]);
            float a2 = __expf(dl * A4[2]), a3 = __expf(dl * A4[3]);
            Bc[0] = fmaf(a0, Bc[0], du * bq0); Ac[0] *= a0;
            Bc[1] = fmaf(a1, Bc[1], du * bq1); Ac[1] *= a1;
            Bc[2] = fmaf(a2, Bc[2], du * bq2); Ac[2] *= a2;
            Bc[3] = fmaf(a3, Bc[3], du * bq3); Ac[3] *= a3;
        }
    }

    // ---- intra-wave inclusive scan over 16 chunks
    #pragma unroll
    for (int s = 1; s < 16; s <<= 1) {
        float pA[4], pB[4];
        #pragma unroll
        for (int e = 0; e < 4; ++e) {
            pA[e] = __shfl_up(Ac[e], 4 * s, 64);
            pB[e] = __shfl_up(Bc[e], 4 * s, 64);
        }
        if (i >= s) {
            #pragma unroll
            for (int e = 0; e < 4; ++e) {
                Bc[e] = fmaf(Ac[e], pB[e], Bc[e]);
                Ac[e] *= pA[e];
            }
        }
    }

    // ---- inter-wave: wave 0 rescans the 16 wave-composites
    if (i == 15) {
        #pragma unroll
        for (int e = 0; e < 4; ++e) {
            s_wA[w][4 * q + e] = Ac[e];
            s_wB[w][4 * q + e] = Bc[e];
        }
    }
    __syncthreads();
    if (w == 0) {
        float wA[4], wB[4];
        #pragma unroll
        for (int e = 0; e < 4; ++e) {
            wA[e] = s_wA[i][4 * q + e];
            wB[e] = s_wB[i][4 * q + e];
        }
        #pragma unroll
        for (int s = 1; s < 16; s <<= 1) {
            float pA[4], pB[4];
            #pragma unroll
            for (int e = 0; e < 4; ++e) {
                pA[e] = __shfl_up(wA[e], 4 * s, 64);
                pB[e] = __shfl_up(wB[e], 4 * s, 64);
            }
            if (i >= s) {
                #pragma unroll
                for (int e = 0; e < 4; ++e) {
                    wB[e] = fmaf(wA[e], pB[e], wB[e]);
                    wA[e] *= pA[e];
                }
            }
        }
        #pragma unroll
        for (int e = 0; e < 4; ++e) s_wB[i][4 * q + e] = wB[e];
    }
    __syncthreads();

    float h[4] = {0.f, 0.f, 0.f, 0.f};
    if (w > 0) {
        #pragma unroll
        for (int e = 0; e < 4; ++e) h[e] = s_wB[w - 1][4 * q + e];
    }
    {
        float pA[4], pB[4];
        #pragma unroll
        for (int e = 0; e < 4; ++e) {
            pA[e] = __shfl_up(Ac[e], 4, 64);
            pB[e] = __shfl_up(Bc[e], 4, 64);
        }
        if (i > 0) {
            #pragma unroll
            for (int e = 0; e < 4; ++e) h[e] = fmaf(pA[e], h[e], pB[e]);
        }
    }

    // ---- pass 2: apply + output
    float Dd = Ds[d];
    int osel = (k == 0) ? 0 : (k == 2) ? 1 : (k == 1) ? 2 : 3;
    float* ob = out + ((size_t)osel * B_ + b) * ((size_t)C_ * L_) + (size_t)c * L_;

    if (fast) {
        #pragma unroll 4
        for (int j = 0; j < 16; ++j) {
            float dl = sd[j], ul = su[j], du = dl * ul;
            uint2 bv = B2[ib + j * st];
            uint2 cv = C2[ib + j * st];
            float b0 = bflo(bv.x), b1 = bfhi(bv.x), b2 = bflo(bv.y), b3 = bfhi(bv.y);
            float c0v = bflo(cv.x), c1v = bfhi(cv.x), c2v = bflo(cv.y), c3v = bfhi(cv.y);
            float r = rj[j];
            float r2 = r * r, r4 = r2 * r2, r8 = r4 * r4;
            float t0 = (q & 1) ? r4 : 1.f;
            float s0 = (q & 2) ? t0 * r8 : t0;
            float a0 = s0 * r, a1 = s0 * r2, a2 = a1 * r, a3 = s0 * r4;
            h[0] = fmaf(a0, h[0], du * b0);
            h[1] = fmaf(a1, h[1], du * b1);
            h[2] = fmaf(a2, h[2], du * b2);
            h[3] = fmaf(a3, h[3], du * b3);
            float y = h[0] * c0v;
            y = fmaf(h[1], c1v, y);
            y = fmaf(h[2], c2v, y);
            y = fmaf(h[3], c3v, y);
            y += __shfl_xor(y, 1, 64);
            y += __shfl_xor(y, 2, 64);
            if (q == 0) {
                y = fmaf(Dd, ul, y);
                int l = g * 16 + j;
                int idx;
                if (k == 0)      idx = l;
                else if (k == 2) idx = L_ - 1 - l;
                else if (k == 1) idx = ((l & 63) << 6) | (l >> 6);
                else { int mm = L_ - 1 - l; idx = ((mm & 63) << 6) | (mm >> 6); }
                ob[idx] = y;
            }
        }
    } else {
        #pragma unroll 4
        for (int j = 0; j < 16; ++j) {
            float dl = sd[j], ul = su[j], du = dl * ul;
            uint2 bv = B2[ib + j * st];
            uint2 cv = C2[ib + j * st];
            float bq0 = bflo(bv.x), bq1 = bfhi(bv.x), bq2 = bflo(bv.y), bq3 = bfhi(bv.y);
            float c0v = bflo(cv.x), c1v = bfhi(cv.x), c2v = bflo(cv.y), c3v = bfhi(cv.y);
            float a0 = __expf(dl * A4[0]), a1 = __expf(dl * A4[1]);
            float a2 = __expf(dl * A4[2]), a3 = __expf(dl * A4[3]);
            h[0] = fmaf(a0, h[0], du * bq0);
            h[1] = fmaf(a1, h[1], du * bq1);
            h[2] = fmaf(a2, h[2], du * bq2);
            h[3] = fmaf(a3, h[3], du * bq3);
            float y = h[0] * c0v;
            y = fmaf(h[1], c1v, y);
            y = fmaf(h[2], c2v, y);
            y = fmaf(h[3], c3v, y);
            y += __shfl_xor(y, 1, 64);
            y += __shfl_xor(y, 2, 64);
            if (q == 0) {
                y = fmaf(Dd, ul, y);
                int l = g * 16 + j;
                int idx;
                if (k == 0)      idx = l;
                else if (k == 2) idx = L_ - 1 - l;
                else if (k == 1) idx = ((l & 63) << 6) | (l >> 6);
                else { int mm = L_ - 1 - l; idx = ((mm & 63) << 6) | (mm >> 6); }
                ob[idx] = y;
            }
        }
    }
}

// ---------------------------------------------------------------------------
extern "C" void kernel_launch(void* const* d_in, const int* in_sizes, int n_in,
                              void* d_out, int out_size, void* d_ws, size_t ws_size,
                              hipStream_t stream) {
    const float* x     = (const float*)d_in[0];
    const float* xpw   = (const float*)d_in[1];
    const float* dpw   = (const float*)d_in[2];
    const float* dpb   = (const float*)d_in[3];
    const float* A_log = (const float*)d_in[4];
    const float* Ds    = (const float*)d_in[5];
    float* out = (float*)d_out;

    float* ws = (float*)d_ws;
    const size_t dL  = (size_t)B_ * K_ * C_ * L_;   // 3,145,728 floats
    const size_t bcL = (size_t)B_ * K_ * L_ * N_;   //   524,288 elements
    const size_t xL  = (size_t)B_ * C_ * L_;        //   786,432 floats
    float*    ws_delta = ws;
    ushort_t* ws_Bm    = (ushort_t*)(ws + dL);      // bcL ushorts
    ushort_t* ws_Cm    = ws_Bm + bcL;               // bcL ushorts
    float*    ws_xT    = ws + dL + bcL;             // (2 bf16 arrays = bcL floats)
    float*    ws_Wt    = ws_xT + xL;                // K*C*40 floats
    int*      ws_flag  = (int*)(ws_Wt + (size_t)K_ * C_ * D40);

    prep_kernel<<<60 + B_ * C_ + 1, 256, 0, stream>>>(
        xpw, x, dpw, dpb, ws_Wt, ws_xT, ws_flag);
    proj_kernel<<<B_ * K_ * (L_ / 64), 512, 0, stream>>>(
        x, ws_xT, ws_Wt, dpw, dpb, ws_flag, ws_delta, ws_Bm, ws_Cm);
    scan_kernel<<<B_ * K_ * C_, 1024, 0, stream>>>(
        ws_delta, x, ws_xT, ws_Bm, ws_Cm, A_log, Ds, ws_flag, out);
}

// Round 7
// 83.855 us; speedup vs baseline: 2.0838x; 1.0289x over previous
//
#include <hip/hip_runtime.h>
#include <math.h>

#define B_ 2
#define C_ 96
#define L_ 4096
#define N_ 16
#define R_ 6
#define K_ 4
#define D38 38
#define D40 40

typedef unsigned short ushort_t;
typedef unsigned int uint_t;

__device__ __forceinline__ uint_t bf16rtn(float f) {
    uint_t u = __float_as_uint(f);
    return (u + 0x7FFFu + ((u >> 16) & 1u)) >> 16;
}
__device__ __forceinline__ float bflo(uint_t p) { return __uint_as_float(p << 16); }
__device__ __forceinline__ float bfhi(uint_t p) { return __uint_as_float(p & 0xFFFF0000u); }

// ---------------------------------------------------------------------------
// Prep: [0,60) weight transpose (K,38,C)->(K,C,40 zero-pad); [60,252) x->xT
// 64x64 per-channel transposes.
// ---------------------------------------------------------------------------
__global__ __launch_bounds__(256) void prep_kernel(
    const float* __restrict__ w, const float* __restrict__ x,
    float* __restrict__ wt, float* __restrict__ xT)
{
    int blk = blockIdx.x;
    int tid = threadIdx.x;
    if (blk < 60) {
        int i = blk * 256 + tid;
        if (i < K_ * C_ * D40) {
            int k   = i / (C_ * D40);
            int rem = i % (C_ * D40);
            int cc  = rem / D40;
            int dd  = rem % D40;
            wt[i] = (dd < D38) ? w[((size_t)k * D38 + dd) * C_ + cc] : 0.f;
        }
    } else {
        __shared__ float t[64][65];
        int bc = blk - 60;
        const float* src = x  + (size_t)bc * L_;
        float*       dst = xT + (size_t)bc * L_;
        int r0  = tid >> 6;
        int col = tid & 63;
        #pragma unroll
        for (int rr = 0; rr < 16; ++rr) {
            int row = rr * 4 + r0;
            t[row][col] = src[row * 64 + col];
        }
        __syncthreads();
        #pragma unroll
        for (int rr = 0; rr < 16; ++rr) {
            int row = rr * 4 + r0;
            dst[row * 64 + col] = t[col][row];
        }
    }
}

// ---------------------------------------------------------------------------
// Kernel 1: projection, fully LDS-staged. All 4 directions computed (no fold:
// the freed CUs would idle anyway). Writes delta (softplus), r = exp(-delta)
// (= 1/(1+e^s), no extra transcendental), and bf16 B/C.
// grid = B*K*(L/64) = 512 blocks x 512 threads.
// ---------------------------------------------------------------------------
__global__ __launch_bounds__(512) void proj_kernel(
    const float* __restrict__ x, const float* __restrict__ xT,
    const float* __restrict__ wt, const float* __restrict__ dpw,
    const float* __restrict__ dpb,
    float* __restrict__ ws_delta, float* __restrict__ ws_r,
    ushort_t* __restrict__ ws_Bm, ushort_t* __restrict__ ws_Cm)
{
    __shared__ float Xs[C_][64];         // 24 KB
    __shared__ float Wsh[C_ * D40];      // 15 KB
    __shared__ float Dwh[C_ * 8];        // 3 KB (6 w + bias, pad 8)
    __shared__ float T2[2][64][41];      // 21 KB

    int tile = blockIdx.x;
    int lt   = tile & 63;
    int bk   = tile >> 6;
    int k    = bk & 3;
    int b    = bk >> 2;

    int tid  = threadIdx.x;
    int l0   = tid & 63;
    int dq   = (tid >> 6) & 3;
    int ch   = tid >> 8;
    int base = dq * 10;                  // cols 38,39 are zero-padded

    // ---- stage x tile (m-order), proj weights, delta weights/bias
    int mt0 = (k >= 2) ? (L_ - 64 * (lt + 1)) : (lt * 64);
    const float* src = ((k & 1) ? xT : x) + (size_t)b * C_ * L_ + mt0;
    #pragma unroll
    for (int s = 0; s < 3; ++s) {
        int idx = tid + s * 512;         // 0..1535 = 96*16 float4s
        int row = idx >> 4, c4 = (idx & 15) << 2;
        *(float4*)&Xs[row][c4] = *(const float4*)(src + (size_t)row * L_ + c4);
    }
    const float* wk = wt + (size_t)k * C_ * D40;
    #pragma unroll
    for (int s = 0; s < 2; ++s) {
        int idx = tid + s * 512;
        if (idx < (C_ * D40 / 4))
            *(float4*)&Wsh[idx * 4] = *(const float4*)(wk + idx * 4);
    }
    if (tid < C_) {
        const float* dwk = dpw + (size_t)k * C_ * R_ + tid * R_;
        #pragma unroll
        for (int r = 0; r < R_; ++r) Dwh[tid * 8 + r] = dwk[r];
        Dwh[tid * 8 + 6] = dpb[k * C_ + tid];
    }
    __syncthreads();

    int xi = (k >= 2) ? (63 - l0) : l0;
    float acc[10];
    #pragma unroll
    for (int t = 0; t < 10; ++t) acc[t] = 0.f;
    int c0 = ch * 48;
    #pragma unroll 4
    for (int cc = 0; cc < 48; ++cc) {
        int c = c0 + cc;
        float xv = Xs[c][xi];
        const float* wc = &Wsh[c * D40 + base];   // wave-uniform -> broadcast
        #pragma unroll
        for (int t = 0; t < 10; ++t) acc[t] = fmaf(xv, wc[t], acc[t]);
    }
    #pragma unroll
    for (int t = 0; t < 10; ++t) T2[ch][l0][base + t] = acc[t];
    __syncthreads();

    // ---- B/C bf16 coalesced stores (uint2 per thread)
    {
        int lq = tid >> 3, sub = tid & 7;
        int buf = sub >> 2, q = sub & 3;
        int col = R_ + buf * 16 + 4 * q;
        float v0 = T2[0][lq][col]     + T2[1][lq][col];
        float v1 = T2[0][lq][col + 1] + T2[1][lq][col + 1];
        float v2 = T2[0][lq][col + 2] + T2[1][lq][col + 2];
        float v3 = T2[0][lq][col + 3] + T2[1][lq][col + 3];
        uint_t p0 = bf16rtn(v0) | (bf16rtn(v1) << 16);
        uint_t p1 = bf16rtn(v2) | (bf16rtn(v3) << 16);
        ushort_t* dst = buf ? ws_Cm : ws_Bm;
        *(uint2*)(dst + ((size_t)bk * L_ + lt * 64 + lq) * N_ + 4 * q) =
            make_uint2(p0, p1);
    }

    // ---- delta projection + softplus + r = exp(-softplus) = 1/(1+e^s)
    float ar[R_];
    #pragma unroll
    for (int r = 0; r < R_; ++r) ar[r] = T2[0][l0][r] + T2[1][l0][r];
    float* dlt = ws_delta + (size_t)bk * C_ * L_ + lt * 64 + l0;
    float* rlt = ws_r     + (size_t)bk * C_ * L_ + lt * 64 + l0;
    int cq = ch * 4 + dq;
    #pragma unroll 2
    for (int cc = 0; cc < 12; ++cc) {
        int c = cc * 8 + cq;
        float s = Dwh[c * 8 + 6];
        #pragma unroll
        for (int r = 0; r < R_; ++r) s = fmaf(ar[r], Dwh[c * 8 + r], s);
        float em = __expf(-fabsf(s));
        float sp = fmaxf(s, 0.f) + log1pf(em);
        float t  = 1.0f / (1.0f + em);
        float rr = (s > 0.f) ? (1.f - t) : t;   // = exp(-softplus(s))
        dlt[(size_t)c * L_] = sp;
        rlt[(size_t)c * L_] = rr;
    }
}

// ---------------------------------------------------------------------------
// Kernel 2: selective scan, 1024 threads per channel. Thread (g,q): chunk of
// 16 l's, n-quad q. Fast path (A[n]==-(n+1)): NO exp anywhere — a_n = r^(n+1)
// with r staged from proj. s_x holds du=delta*u (fast) or raw delta (slow).
// ---------------------------------------------------------------------------
#define SR 17

__global__ __launch_bounds__(1024, 8) void scan_kernel(
    const float* __restrict__ ws_delta, const float* __restrict__ ws_r,
    const float* __restrict__ x, const float* __restrict__ xT,
    const ushort_t* __restrict__ ws_Bm, const ushort_t* __restrict__ ws_Cm,
    const float* __restrict__ A_log, const float* __restrict__ Ds,
    float* __restrict__ out)
{
    __shared__ float s_x[16][16 * SR];
    __shared__ float s_u[16][16 * SR];
    __shared__ float s_r[16][16 * SR];
    __shared__ float s_wA[16][N_];
    __shared__ float s_wB[16][N_];

    int chn = blockIdx.x;
    int c  = chn % C_;
    int k  = (chn / C_) % K_;
    int b  = chn / (C_ * K_);
    int bk = b * K_ + k;
    int d  = k * C_ + c;

    int tid  = threadIdx.x;
    int w    = tid >> 6;
    int lane = tid & 63;
    int i    = lane >> 2;
    int q    = lane & 3;
    int g    = w * 16 + i;

    float A4[4];
    bool okl = true;
    #pragma unroll
    for (int e = 0; e < 4; ++e) {
        A4[e] = -__expf(A_log[(size_t)d * N_ + 4 * q + e]);
        okl &= (fabsf(A4[e] + (float)(4 * q + e + 1)) < 1e-3f);
    }
    int fast = __all(okl);

    // ---- stage {du|delta, u, r} (per-wave private; no barrier needed)
    {
        int e = lane * 4;
        int row = e >> 4, col = e & 15;
        const float* dp = ws_delta + (size_t)chn * L_ + w * 256;
        const float* rp = ws_r     + (size_t)chn * L_ + w * 256;
        float4 vd = *(const float4*)(dp + e);
        float4 vr = *(const float4*)(rp + e);
        const float* usrc = ((k & 1) ? xT : x) + ((size_t)b * C_ + c) * L_;
        float4 vu;
        if (k < 2) {
            vu = *(const float4*)(usrc + w * 256 + e);
        } else {
            float4 t4 = *(const float4*)(usrc + (L_ - 4 - w * 256 - e));
            vu = make_float4(t4.w, t4.z, t4.y, t4.x);
        }
        float4 vx = fast ? make_float4(vd.x * vu.x, vd.y * vu.y,
                                       vd.z * vu.z, vd.w * vu.w)
                         : vd;
        *(float4*)(s_x[w] + row * SR + col) = vx;
        *(float4*)(s_u[w] + row * SR + col) = vu;
        *(float4*)(s_r[w] + row * SR + col) = vr;
    }

    const float* sx = s_x[w] + i * SR;
    const float* su = s_u[w] + i * SR;
    const float* sr = s_r[w] + i * SR;
    const uint2* B2 = (const uint2*)(ws_Bm + (size_t)bk * ((size_t)L_ * N_));
    const uint2* C2 = (const uint2*)(ws_Cm + (size_t)bk * ((size_t)L_ * N_));
    int ib = (g * 16) * 4 + q;

    float Ac[4] = {1.f, 1.f, 1.f, 1.f};
    float Bc[4] = {0.f, 0.f, 0.f, 0.f};

    // ---- pass 1: chunk composite
    if (fast) {
        float Rc = 1.f;
        #pragma unroll 4
        for (int j = 0; j < 16; ++j) {
            float du = sx[j];
            float r  = sr[j];
            uint2 bv = B2[ib + j * 4];
            float b0 = bflo(bv.x), b1 = bfhi(bv.x), b2 = bflo(bv.y), b3 = bfhi(bv.y);
            float r2 = r * r, r4 = r2 * r2, r8 = r4 * r4;
            float t0 = (q & 1) ? r4 : 1.f;
            float s0 = (q & 2) ? t0 * r8 : t0;
            float a0 = s0 * r, a1 = s0 * r2, a2 = a1 * r, a3 = s0 * r4;
            Bc[0] = fmaf(a0, Bc[0], du * b0);
            Bc[1] = fmaf(a1, Bc[1], du * b1);
            Bc[2] = fmaf(a2, Bc[2], du * b2);
            Bc[3] = fmaf(a3, Bc[3], du * b3);
            Rc *= r;
        }
        float R2 = Rc * Rc, R4 = R2 * R2, R8 = R4 * R4;
        float t0 = (q & 1) ? R4 : 1.f;
        float s0 = (q & 2) ? t0 * R8 : t0;
        Ac[0] = s0 * Rc; Ac[1] = s0 * R2; Ac[2] = Ac[1] * Rc; Ac[3] = s0 * R4;
    } else {
        #pragma unroll 4
        for (int j = 0; j < 16; ++j) {
            float dl = sx[j], ul = su[j], du = dl * ul;
            uint2 bv = B2[ib + j * 4];
            float bq0 = bflo(bv.x), bq1 = bfhi(bv.x), bq2 = bflo(bv.y), bq3 = bfhi(bv.y);
            float a0 = __expf(dl * A4[0]), a1 = __expf(dl * A4[1]);
            float a2 = __expf(dl * A4[2]), a3 = __expf(dl * A4[3]);
            Bc[0] = fmaf(a0, Bc[0], du * bq0); Ac[0] *= a0;
            Bc[1] = fmaf(a1, Bc[1], du * bq1); Ac[1] *= a1;
            Bc[2] = fmaf(a2, Bc[2], du * bq2); Ac[2] *= a2;
            Bc[3] = fmaf(a3, Bc[3], du * bq3); Ac[3] *= a3;
        }
    }

    // ---- intra-wave inclusive scan over 16 chunks
    #pragma unroll
    for (int s = 1; s < 16; s <<= 1) {
        float pA[4], pB[4];
        #pragma unroll
        for (int e = 0; e < 4; ++e) {
            pA[e] = __shfl_up(Ac[e], 4 * s, 64);
            pB[e] = __shfl_up(Bc[e], 4 * s, 64);
        }
        if (i >= s) {
            #pragma unroll
            for (int e = 0; e < 4; ++e) {
                Bc[e] = fmaf(Ac[e], pB[e], Bc[e]);
                Ac[e] *= pA[e];
            }
        }
    }

    // ---- inter-wave: wave 0 rescans the 16 wave-composites
    if (i == 15) {
        #pragma unroll
        for (int e = 0; e < 4; ++e) {
            s_wA[w][4 * q + e] = Ac[e];
            s_wB[w][4 * q + e] = Bc[e];
        }
    }
    __syncthreads();
    if (w == 0) {
        float wA[4], wB[4];
        #pragma unroll
        for (int e = 0; e < 4; ++e) {
            wA[e] = s_wA[i][4 * q + e];
            wB[e] = s_wB[i][4 * q + e];
        }
        #pragma unroll
        for (int s = 1; s < 16; s <<= 1) {
            float pA[4], pB[4];
            #pragma unroll
            for (int e = 0; e < 4; ++e) {
                pA[e] = __shfl_up(wA[e], 4 * s, 64);
                pB[e] = __shfl_up(wB[e], 4 * s, 64);
            }
            if (i >= s) {
                #pragma unroll
                for (int e = 0; e < 4; ++e) {
                    wB[e] = fmaf(wA[e], pB[e], wB[e]);
                    wA[e] *= pA[e];
                }
            }
        }
        #pragma unroll
        for (int e = 0; e < 4; ++e) s_wB[i][4 * q + e] = wB[e];
    }
    __syncthreads();

    float h[4] = {0.f, 0.f, 0.f, 0.f};
    if (w > 0) {
        #pragma unroll
        for (int e = 0; e < 4; ++e) h[e] = s_wB[w - 1][4 * q + e];
    }
    {
        float pA[4], pB[4];
        #pragma unroll
        for (int e = 0; e < 4; ++e) {
            pA[e] = __shfl_up(Ac[e], 4, 64);
            pB[e] = __shfl_up(Bc[e], 4, 64);
        }
        if (i > 0) {
            #pragma unroll
            for (int e = 0; e < 4; ++e) h[e] = fmaf(pA[e], h[e], pB[e]);
        }
    }

    // ---- pass 2: apply + output
    float Dd = Ds[d];
    int osel = (k == 0) ? 0 : (k == 2) ? 1 : (k == 1) ? 2 : 3;
    float* ob = out + ((size_t)osel * B_ + b) * ((size_t)C_ * L_) + (size_t)c * L_;

    if (fast) {
        #pragma unroll 4
        for (int j = 0; j < 16; ++j) {
            float du = sx[j];
            float r  = sr[j];
            uint2 bv = B2[ib + j * 4];
            uint2 cv = C2[ib + j * 4];
            float b0 = bflo(bv.x), b1 = bfhi(bv.x), b2 = bflo(bv.y), b3 = bfhi(bv.y);
            float c0v = bflo(cv.x), c1v = bfhi(cv.x), c2v = bflo(cv.y), c3v = bfhi(cv.y);
            float r2 = r * r, r4 = r2 * r2, r8 = r4 * r4;
            float t0 = (q & 1) ? r4 : 1.f;
            float s0 = (q & 2) ? t0 * r8 : t0;
            float a0 = s0 * r, a1 = s0 * r2, a2 = a1 * r, a3 = s0 * r4;
            h[0] = fmaf(a0, h[0], du * b0);
            h[1] = fmaf(a1, h[1], du * b1);
            h[2] = fmaf(a2, h[2], du * b2);
            h[3] = fmaf(a3, h[3], du * b3);
            float y = h[0] * c0v;
            y = fmaf(h[1], c1v, y);
            y = fmaf(h[2], c2v, y);
            y = fmaf(h[3], c3v, y);
            y += __shfl_xor(y, 1, 64);
            y += __shfl_xor(y, 2, 64);
            if (q == 0) {
                y = fmaf(Dd, su[j], y);
                int l = g * 16 + j;
                int idx;
                if (k == 0)      idx = l;
                else if (k == 2) idx = L_ - 1 - l;
                else if (k == 1) idx = ((l & 63) << 6) | (l >> 6);
                else { int mm = L_ - 1 - l; idx = ((mm & 63) << 6) | (mm >> 6); }
                ob[idx] = y;
            }
        }
    } else {
        #pragma unroll 4
        for (int j = 0; j < 16; ++j) {
            float dl = sx[j], ul = su[j], du = dl * ul;
            uint2 bv = B2[ib + j * 4];
            uint2 cv = C2[ib + j * 4];
            float bq0 = bflo(bv.x), bq1 = bfhi(bv.x), bq2 = bflo(bv.y), bq3 = bfhi(bv.y);
            float c0v = bflo(cv.x), c1v = bfhi(cv.x), c2v = bflo(cv.y), c3v = bfhi(cv.y);
            float a0 = __expf(dl * A4[0]), a1 = __expf(dl * A4[1]);
            float a2 = __expf(dl * A4[2]), a3 = __expf(dl * A4[3]);
            h[0] = fmaf(a0, h[0], du * bq0);
            h[1] = fmaf(a1, h[1], du * bq1);
            h[2] = fmaf(a2, h[2], du * bq2);
            h[3] = fmaf(a3, h[3], du * bq3);
            float y = h[0] * c0v;
            y = fmaf(h[1], c1v, y);
            y = fmaf(h[2], c2v, y);
            y = fmaf(h[3], c3v, y);
            y += __shfl_xor(y, 1, 64);
            y += __shfl_xor(y, 2, 64);
            if (q == 0) {
                y = fmaf(Dd, ul, y);
                int l = g * 16 + j;
                int idx;
                if (k == 0)      idx = l;
                else if (k == 2) idx = L_ - 1 - l;
                else if (k == 1) idx = ((l & 63) << 6) | (l >> 6);
                else { int mm = L_ - 1 - l; idx = ((mm & 63) << 6) | (mm >> 6); }
                ob[idx] = y;
            }
        }
    }
}

// ---------------------------------------------------------------------------
extern "C" void kernel_launch(void* const* d_in, const int* in_sizes, int n_in,
                              void* d_out, int out_size, void* d_ws, size_t ws_size,
                              hipStream_t stream) {
    const float* x     = (const float*)d_in[0];
    const float* xpw   = (const float*)d_in[1];
    const float* dpw   = (const float*)d_in[2];
    const float* dpb   = (const float*)d_in[3];
    const float* A_log = (const float*)d_in[4];
    const float* Ds    = (const float*)d_in[5];
    float* out = (float*)d_out;

    float* ws = (float*)d_ws;
    const size_t dL  = (size_t)B_ * K_ * C_ * L_;   // 3,145,728 floats
    const size_t bcL = (size_t)B_ * K_ * L_ * N_;   //   524,288 elements
    const size_t xL  = (size_t)B_ * C_ * L_;        //   786,432 floats
    float*    ws_delta = ws;                         // dL floats
    float*    ws_r     = ws + dL;                    // dL floats
    ushort_t* ws_Bm    = (ushort_t*)(ws + 2 * dL);   // bcL ushorts
    ushort_t* ws_Cm    = ws_Bm + bcL;                // bcL ushorts
    float*    ws_xT    = ws + 2 * dL + bcL;          // (2 bf16 arrays = bcL floats)
    float*    ws_Wt    = ws_xT + xL;                 // K*C*40 floats
    // total ~30.6 MB

    prep_kernel<<<60 + B_ * C_, 256, 0, stream>>>(xpw, x, ws_Wt, ws_xT);
    proj_kernel<<<B_ * K_ * (L_ / 64), 512, 0, stream>>>(
        x, ws_xT, ws_Wt, dpw, dpb, ws_delta, ws_r, ws_Bm, ws_Cm);
    scan_kernel<<<B_ * K_ * C_, 1024, 0, stream>>>(
        ws_delta, ws_r, x, ws_xT, ws_Bm, ws_Cm, A_log, Ds, out);
}

// Round 8
// 73.236 us; speedup vs baseline: 2.3859x; 1.1450x over previous
//
#include <hip/hip_runtime.h>
#include <math.h>

#define B_ 2
#define C_ 96
#define L_ 4096
#define N_ 16
#define R_ 6
#define K_ 4
#define D38 38
#define D40 40
#define SRW 20   // padded LDS row stride (floats): 16-B aligned rows, <=2-way banks

typedef unsigned short ushort_t;
typedef unsigned int uint_t;

__device__ __forceinline__ uint_t bf16rtn(float f) {
    uint_t u = __float_as_uint(f);
    return (u + 0x7FFFu + ((u >> 16) & 1u)) >> 16;
}
__device__ __forceinline__ float bflo(uint_t p) { return __uint_as_float(p << 16); }
__device__ __forceinline__ float bfhi(uint_t p) { return __uint_as_float(p & 0xFFFF0000u); }

#define GETC(v, jj) ((jj) == 0 ? (v).x : (jj) == 1 ? (v).y : (jj) == 2 ? (v).z : (v).w)

// ---------------------------------------------------------------------------
// Prep: [0,60) weight transpose (K,38,C)->(K,C,40 zero-pad); [60,252) x->xT
// 64x64 per-channel transposes; block 252: fast-path flag (A[n]==-(n+1)?).
// ---------------------------------------------------------------------------
__global__ __launch_bounds__(256) void prep_kernel(
    const float* __restrict__ w, const float* __restrict__ x,
    const float* __restrict__ A_log,
    float* __restrict__ wt, float* __restrict__ xT, int* __restrict__ flag)
{
    int blk = blockIdx.x;
    int tid = threadIdx.x;
    if (blk < 60) {
        int i = blk * 256 + tid;
        if (i < K_ * C_ * D40) {
            int k   = i / (C_ * D40);
            int rem = i % (C_ * D40);
            int cc  = rem / D40;
            int dd  = rem % D40;
            wt[i] = (dd < D38) ? w[((size_t)k * D38 + dd) * C_ + cc] : 0.f;
        }
    } else if (blk < 60 + B_ * C_) {
        __shared__ float t[64][65];
        int bc = blk - 60;
        const float* src = x  + (size_t)bc * L_;
        float*       dst = xT + (size_t)bc * L_;
        int r0  = tid >> 6;
        int col = tid & 63;
        #pragma unroll
        for (int rr = 0; rr < 16; ++rr) {
            int row = rr * 4 + r0;
            t[row][col] = src[row * 64 + col];
        }
        __syncthreads();
        #pragma unroll
        for (int rr = 0; rr < 16; ++rr) {
            int row = rr * 4 + r0;
            dst[row * 64 + col] = t[col][row];
        }
    } else {
        bool ok = true;
        for (int i = tid; i < K_ * C_ * N_; i += 256) {
            float a = __expf(A_log[i]);
            ok = ok && (fabsf(a - (float)((i & 15) + 1)) < 1e-3f);
        }
        __shared__ int sok[4];
        unsigned long long m = __ballot(ok);
        if ((tid & 63) == 0) sok[tid >> 6] = (m == 0xFFFFFFFFFFFFFFFFull) ? 1 : 0;
        __syncthreads();
        if (tid == 0) flag[0] = sok[0] & sok[1] & sok[2] & sok[3];
    }
}

// ---------------------------------------------------------------------------
// Kernel 1: projection. X tile in LDS; weights via wave-uniform SCALAR loads
// (readfirstlane-forced -> s_load, off the LDS pipe). Writes:
//   ws_x = du = delta*u (fast) or delta (slow), ws_r = exp(-delta),
//   B/C bf16 in chunk-transposed layout (bk, j=l%16, g=l/16, q) for scan
//   lane-contiguous reads. grid = B*K*(L/64) = 512 blocks x 512 threads.
// ---------------------------------------------------------------------------
__global__ __launch_bounds__(512) void proj_kernel(
    const float* __restrict__ x, const float* __restrict__ xT,
    const float* __restrict__ wt, const float* __restrict__ dpw,
    const float* __restrict__ dpb, const int* __restrict__ flagp,
    float* __restrict__ ws_x, float* __restrict__ ws_r,
    ushort_t* __restrict__ ws_Bm, ushort_t* __restrict__ ws_Cm)
{
    __shared__ float Xs[C_][64];         // 24 KB
    __shared__ float T2[2][64][41];      // 21 KB

    int tile = blockIdx.x;
    int lt   = tile & 63;
    int bk   = tile >> 6;
    int k    = bk & 3;
    int b    = bk >> 2;

    int tid  = threadIdx.x;
    int l0   = tid & 63;
    int dq_u = __builtin_amdgcn_readfirstlane((tid >> 6) & 3);
    int ch_u = __builtin_amdgcn_readfirstlane(tid >> 8);
    int base = dq_u * 10;                // cols 38,39 zero-padded
    int flagv = flagp[0];

    // ---- stage x tile (m-order)
    int mt0 = (k >= 2) ? (L_ - 64 * (lt + 1)) : (lt * 64);
    const float* src = ((k & 1) ? xT : x) + (size_t)b * C_ * L_ + mt0;
    #pragma unroll
    for (int s = 0; s < 3; ++s) {
        int idx = tid + s * 512;         // 0..1535 = 96*16 float4s
        int row = idx >> 4, c4 = (idx & 15) << 2;
        *(float4*)&Xs[row][c4] = *(const float4*)(src + (size_t)row * L_ + c4);
    }
    __syncthreads();

    int xi = (k >= 2) ? (63 - l0) : l0;
    const float* wk = wt + k * C_ * D40 + base;
    float acc[10];
    #pragma unroll
    for (int t = 0; t < 10; ++t) acc[t] = 0.f;
    int c0 = ch_u * 48;
    #pragma unroll 4
    for (int cc = 0; cc < 48; ++cc) {
        int c = c0 + cc;
        float xv = Xs[c][xi];
        const float* wc = wk + c * D40;  // uniform -> s_load
        #pragma unroll
        for (int t = 0; t < 10; ++t) acc[t] = fmaf(xv, wc[t], acc[t]);
    }
    #pragma unroll
    for (int t = 0; t < 10; ++t) T2[ch_u][l0][base + t] = acc[t];
    __syncthreads();

    // ---- B/C bf16 stores, chunk-transposed: uint2 idx = ((bk*16+j)*256+g)*4+q
    {
        int lq = tid >> 3, sub = tid & 7;
        int buf = sub >> 2, q = sub & 3;
        int col = R_ + buf * 16 + 4 * q;
        float v0 = T2[0][lq][col]     + T2[1][lq][col];
        float v1 = T2[0][lq][col + 1] + T2[1][lq][col + 1];
        float v2 = T2[0][lq][col + 2] + T2[1][lq][col + 2];
        float v3 = T2[0][lq][col + 3] + T2[1][lq][col + 3];
        uint_t p0 = bf16rtn(v0) | (bf16rtn(v1) << 16);
        uint_t p1 = bf16rtn(v2) | (bf16rtn(v3) << 16);
        int l = lt * 64 + lq;
        int j = l & 15, g = l >> 4;
        size_t o = (size_t)bk * 16384 + j * 1024 + g * 4 + q;
        uint2* dst = (uint2*)(buf ? ws_Cm : ws_Bm);
        dst[o] = make_uint2(p0, p1);
    }

    // ---- delta projection + softplus + r; store du (fast) or delta (slow)
    float ar[R_];
    #pragma unroll
    for (int r = 0; r < R_; ++r) ar[r] = T2[0][l0][r] + T2[1][l0][r];
    float* xlt = ws_x + (size_t)bk * C_ * L_ + lt * 64 + l0;
    float* rlt = ws_r + (size_t)bk * C_ * L_ + lt * 64 + l0;
    int cq_u = ch_u * 4 + dq_u;
    #pragma unroll 2
    for (int cc = 0; cc < 12; ++cc) {
        int c = cc * 8 + cq_u;
        const float* dc = dpw + (k * C_ + c) * R_;   // uniform -> s_load
        float s = dpb[k * C_ + c];
        #pragma unroll
        for (int r = 0; r < R_; ++r) s = fmaf(ar[r], dc[r], s);
        float em = __expf(-fabsf(s));
        float sp = fmaxf(s, 0.f) + log1pf(em);
        float t  = 1.0f / (1.0f + em);
        float rr = (s > 0.f) ? (1.f - t) : t;        // exp(-softplus(s))
        float uv = Xs[c][xi];
        xlt[(size_t)c * L_] = flagv ? (sp * uv) : sp;
        rlt[(size_t)c * L_] = rr;
    }
}

// ---------------------------------------------------------------------------
// Kernel 2: selective scan, 1024 threads per channel. Thread (g,q): chunk of
// 16 l's, n-quad q. Fast path: no exp (a_n = r^(n+1), du pre-multiplied).
// float4 LDS reads per 4-j; lane-contiguous B/C loads; k-even float4 stores.
// ---------------------------------------------------------------------------
__global__ __launch_bounds__(1024, 8) void scan_kernel(
    const float* __restrict__ ws_x, const float* __restrict__ ws_r,
    const float* __restrict__ x, const float* __restrict__ xT,
    const ushort_t* __restrict__ ws_Bm, const ushort_t* __restrict__ ws_Cm,
    const float* __restrict__ A_log, const float* __restrict__ Ds,
    const int* __restrict__ flagp, float* __restrict__ out)
{
    __shared__ __align__(16) float s_x[16][16 * SRW];
    __shared__ __align__(16) float s_u[16][16 * SRW];
    __shared__ __align__(16) float s_r[16][16 * SRW];
    __shared__ float s_wA[16][N_];
    __shared__ float s_wB[16][N_];

    int chn = blockIdx.x;
    int c  = chn % C_;
    int k  = (chn / C_) % K_;
    int b  = chn / (C_ * K_);
    int bk = b * K_ + k;
    int d  = k * C_ + c;

    int tid  = threadIdx.x;
    int w    = tid >> 6;
    int lane = tid & 63;
    int i    = lane >> 2;
    int q    = lane & 3;
    int g    = w * 16 + i;

    int fast = flagp[0];
    float A4[4];
    if (!fast) {
        #pragma unroll
        for (int e = 0; e < 4; ++e)
            A4[e] = -__expf(A_log[(size_t)d * N_ + 4 * q + e]);
    }

    // ---- stage du|delta, r, u (per-wave private)
    {
        int e = lane * 4;
        int row = e >> 4, col = e & 15;
        float4 vx = *(const float4*)(ws_x + (size_t)chn * L_ + w * 256 + e);
        float4 vr = *(const float4*)(ws_r + (size_t)chn * L_ + w * 256 + e);
        const float* usrc = ((k & 1) ? xT : x) + ((size_t)b * C_ + c) * L_;
        float4 vu;
        if (k < 2) {
            vu = *(const float4*)(usrc + w * 256 + e);
        } else {
            float4 t4 = *(const float4*)(usrc + (L_ - 4 - w * 256 - e));
            vu = make_float4(t4.w, t4.z, t4.y, t4.x);
        }
        *(float4*)(s_x[w] + row * SRW + col) = vx;
        *(float4*)(s_r[w] + row * SRW + col) = vr;
        *(float4*)(s_u[w] + row * SRW + col) = vu;
    }

    const float* sx = s_x[w] + i * SRW;
    const float* su = s_u[w] + i * SRW;
    const float* sr = s_r[w] + i * SRW;
    const uint2* B2 = (const uint2*)ws_Bm;
    const uint2* C2 = (const uint2*)ws_Cm;
    int ibase = bk * 16384 + g * 4 + q;  // + j*1024 per j

    float Ac[4] = {1.f, 1.f, 1.f, 1.f};
    float Bc[4] = {0.f, 0.f, 0.f, 0.f};

    // ---- pass 1: chunk composite
    if (fast) {
        float Rc = 1.f;
        #pragma unroll
        for (int jq = 0; jq < 4; ++jq) {
            float4 xq = *(const float4*)(sx + jq * 4);
            float4 rq = *(const float4*)(sr + jq * 4);
            #pragma unroll
            for (int jj = 0; jj < 4; ++jj) {
                int j = jq * 4 + jj;
                float du = GETC(xq, jj);
                float r  = GETC(rq, jj);
                uint2 bv = B2[ibase + j * 1024];
                float b0 = bflo(bv.x), b1 = bfhi(bv.x);
                float b2 = bflo(bv.y), b3 = bfhi(bv.y);
                float r2 = r * r, r4 = r2 * r2, r8 = r4 * r4;
                float t0 = (q & 1) ? r4 : 1.f;
                float s0 = (q & 2) ? t0 * r8 : t0;
                float a0 = s0 * r, a1 = s0 * r2, a2 = a1 * r, a3 = s0 * r4;
                Bc[0] = fmaf(a0, Bc[0], du * b0);
                Bc[1] = fmaf(a1, Bc[1], du * b1);
                Bc[2] = fmaf(a2, Bc[2], du * b2);
                Bc[3] = fmaf(a3, Bc[3], du * b3);
                Rc *= r;
            }
        }
        float R2 = Rc * Rc, R4 = R2 * R2, R8 = R4 * R4;
        float t0 = (q & 1) ? R4 : 1.f;
        float s0 = (q & 2) ? t0 * R8 : t0;
        Ac[0] = s0 * Rc; Ac[1] = s0 * R2; Ac[2] = Ac[1] * Rc; Ac[3] = s0 * R4;
    } else {
        #pragma unroll 4
        for (int j = 0; j < 16; ++j) {
            float dl = sx[j], ul = su[j], du = dl * ul;
            uint2 bv = B2[ibase + j * 1024];
            float b0 = bflo(bv.x), b1 = bfhi(bv.x);
            float b2 = bflo(bv.y), b3 = bfhi(bv.y);
            float a0 = __expf(dl * A4[0]), a1 = __expf(dl * A4[1]);
            float a2 = __expf(dl * A4[2]), a3 = __expf(dl * A4[3]);
            Bc[0] = fmaf(a0, Bc[0], du * b0); Ac[0] *= a0;
            Bc[1] = fmaf(a1, Bc[1], du * b1); Ac[1] *= a1;
            Bc[2] = fmaf(a2, Bc[2], du * b2); Ac[2] *= a2;
            Bc[3] = fmaf(a3, Bc[3], du * b3); Ac[3] *= a3;
        }
    }

    // ---- intra-wave inclusive scan over 16 chunks
    #pragma unroll
    for (int s = 1; s < 16; s <<= 1) {
        float pA[4], pB[4];
        #pragma unroll
        for (int e = 0; e < 4; ++e) {
            pA[e] = __shfl_up(Ac[e], 4 * s, 64);
            pB[e] = __shfl_up(Bc[e], 4 * s, 64);
        }
        if (i >= s) {
            #pragma unroll
            for (int e = 0; e < 4; ++e) {
                Bc[e] = fmaf(Ac[e], pB[e], Bc[e]);
                Ac[e] *= pA[e];
            }
        }
    }

    // ---- inter-wave: wave 0 rescans the 16 wave-composites
    if (i == 15) {
        #pragma unroll
        for (int e = 0; e < 4; ++e) {
            s_wA[w][4 * q + e] = Ac[e];
            s_wB[w][4 * q + e] = Bc[e];
        }
    }
    __syncthreads();
    if (w == 0) {
        float wA[4], wB[4];
        #pragma unroll
        for (int e = 0; e < 4; ++e) {
            wA[e] = s_wA[i][4 * q + e];
            wB[e] = s_wB[i][4 * q + e];
        }
        #pragma unroll
        for (int s = 1; s < 16; s <<= 1) {
            float pA[4], pB[4];
            #pragma unroll
            for (int e = 0; e < 4; ++e) {
                pA[e] = __shfl_up(wA[e], 4 * s, 64);
                pB[e] = __shfl_up(wB[e], 4 * s, 64);
            }
            if (i >= s) {
                #pragma unroll
                for (int e = 0; e < 4; ++e) {
                    wB[e] = fmaf(wA[e], pB[e], wB[e]);
                    wA[e] *= pA[e];
                }
            }
        }
        #pragma unroll
        for (int e = 0; e < 4; ++e) s_wB[i][4 * q + e] = wB[e];
    }
    __syncthreads();

    float h[4] = {0.f, 0.f, 0.f, 0.f};
    if (w > 0) {
        #pragma unroll
        for (int e = 0; e < 4; ++e) h[e] = s_wB[w - 1][4 * q + e];
    }
    {
        float pA[4], pB[4];
        #pragma unroll
        for (int e = 0; e < 4; ++e) {
            pA[e] = __shfl_up(Ac[e], 4, 64);
            pB[e] = __shfl_up(Bc[e], 4, 64);
        }
        if (i > 0) {
            #pragma unroll
            for (int e = 0; e < 4; ++e) h[e] = fmaf(pA[e], h[e], pB[e]);
        }
    }

    // ---- pass 2: apply + output
    float Dd = Ds[d];
    int osel = (k == 0) ? 0 : (k == 2) ? 1 : (k == 1) ? 2 : 3;
    float* ob = out + ((size_t)osel * B_ + b) * ((size_t)C_ * L_) + (size_t)c * L_;
    int gl = g * 16;

    if (fast) {
        #pragma unroll
        for (int jq = 0; jq < 4; ++jq) {
            float4 xq = *(const float4*)(sx + jq * 4);
            float4 rq = *(const float4*)(sr + jq * 4);
            float4 uq = *(const float4*)(su + jq * 4);
            float yb0, yb1, yb2, yb3;
            #pragma unroll
            for (int jj = 0; jj < 4; ++jj) {
                int j = jq * 4 + jj;
                float du = GETC(xq, jj);
                float r  = GETC(rq, jj);
                uint2 bv = B2[ibase + j * 1024];
                uint2 cv = C2[ibase + j * 1024];
                float b0 = bflo(bv.x), b1 = bfhi(bv.x);
                float b2 = bflo(bv.y), b3 = bfhi(bv.y);
                float c0v = bflo(cv.x), c1v = bfhi(cv.x);
                float c2v = bflo(cv.y), c3v = bfhi(cv.y);
                float r2 = r * r, r4 = r2 * r2, r8 = r4 * r4;
                float t0 = (q & 1) ? r4 : 1.f;
                float s0 = (q & 2) ? t0 * r8 : t0;
                float a0 = s0 * r, a1 = s0 * r2, a2 = a1 * r, a3 = s0 * r4;
                h[0] = fmaf(a0, h[0], du * b0);
                h[1] = fmaf(a1, h[1], du * b1);
                h[2] = fmaf(a2, h[2], du * b2);
                h[3] = fmaf(a3, h[3], du * b3);
                float y = h[0] * c0v;
                y = fmaf(h[1], c1v, y);
                y = fmaf(h[2], c2v, y);
                y = fmaf(h[3], c3v, y);
                y += __shfl_xor(y, 1, 64);
                y += __shfl_xor(y, 2, 64);
                y = fmaf(Dd, GETC(uq, jj), y);
                if (jj == 0) yb0 = y; else if (jj == 1) yb1 = y;
                else if (jj == 2) yb2 = y; else yb3 = y;
                if ((k & 1) && q == 0) {
                    int l = gl + j;
                    int mm = (k == 1) ? l : (L_ - 1 - l);
                    ob[((mm & 63) << 6) | (mm >> 6)] = y;
                }
            }
            if (!(k & 1) && q == 0) {
                if (k == 0) {
                    *(float4*)(ob + gl + jq * 4) = make_float4(yb0, yb1, yb2, yb3);
                } else {
                    *(float4*)(ob + (L_ - 4 - gl - jq * 4)) =
                        make_float4(yb3, yb2, yb1, yb0);
                }
            }
        }
    } else {
        #pragma unroll 4
        for (int j = 0; j < 16; ++j) {
            float dl = sx[j], ul = su[j], du = dl * ul;
            uint2 bv = B2[ibase + j * 1024];
            uint2 cv = C2[ibase + j * 1024];
            float b0 = bflo(bv.x), b1 = bfhi(bv.x);
            float b2 = bflo(bv.y), b3 = bfhi(bv.y);
            float c0v = bflo(cv.x), c1v = bfhi(cv.x);
            float c2v = bflo(cv.y), c3v = bfhi(cv.y);
            float a0 = __expf(dl * A4[0]), a1 = __expf(dl * A4[1]);
            float a2 = __expf(dl * A4[2]), a3 = __expf(dl * A4[3]);
            h[0] = fmaf(a0, h[0], du * b0);
            h[1] = fmaf(a1, h[1], du * b1);
            h[2] = fmaf(a2, h[2], du * b2);
            h[3] = fmaf(a3, h[3], du * b3);
            float y = h[0] * c0v;
            y = fmaf(h[1], c1v, y);
            y = fmaf(h[2], c2v, y);
            y = fmaf(h[3], c3v, y);
            y += __shfl_xor(y, 1, 64);
            y += __shfl_xor(y, 2, 64);
            if (q == 0) {
                y = fmaf(Dd, ul, y);
                int l = gl + j;
                int idx;
                if (k == 0)      idx = l;
                else if (k == 2) idx = L_ - 1 - l;
                else if (k == 1) idx = ((l & 63) << 6) | (l >> 6);
                else { int mm = L_ - 1 - l; idx = ((mm & 63) << 6) | (mm >> 6); }
                ob[idx] = y;
            }
        }
    }
}

// ---------------------------------------------------------------------------
extern "C" void kernel_launch(void* const* d_in, const int* in_sizes, int n_in,
                              void* d_out, int out_size, void* d_ws, size_t ws_size,
                              hipStream_t stream) {
    const float* x     = (const float*)d_in[0];
    const float* xpw   = (const float*)d_in[1];
    const float* dpw   = (const float*)d_in[2];
    const float* dpb   = (const float*)d_in[3];
    const float* A_log = (const float*)d_in[4];
    const float* Ds    = (const float*)d_in[5];
    float* out = (float*)d_out;

    float* ws = (float*)d_ws;
    const size_t dL  = (size_t)B_ * K_ * C_ * L_;   // 3,145,728 floats
    const size_t bcL = (size_t)B_ * K_ * L_ * N_;   //   524,288 bf16 elements
    const size_t xL  = (size_t)B_ * C_ * L_;        //   786,432 floats
    float*    ws_x  = ws;                            // dL floats
    float*    ws_r  = ws + dL;                       // dL floats
    ushort_t* ws_Bm = (ushort_t*)(ws + 2 * dL);      // bcL ushorts
    ushort_t* ws_Cm = ws_Bm + bcL;                   // bcL ushorts
    float*    ws_xT = ws + 2 * dL + bcL;             // xL floats
    float*    ws_Wt = ws_xT + xL;                    // K*C*40 floats
    int*      ws_fl = (int*)(ws_Wt + (size_t)K_ * C_ * D40);

    prep_kernel<<<60 + B_ * C_ + 1, 256, 0, stream>>>(
        xpw, x, A_log, ws_Wt, ws_xT, ws_fl);
    proj_kernel<<<B_ * K_ * (L_ / 64), 512, 0, stream>>>(
        x, ws_xT, ws_Wt, dpw, dpb, ws_fl, ws_x, ws_r, ws_Bm, ws_Cm);
    scan_kernel<<<B_ * K_ * C_, 1024, 0, stream>>>(
        ws_x, ws_r, x, ws_xT, ws_Bm, ws_Cm, A_log, Ds, ws_fl, out);
}